// Round 4
// baseline (281.892 us; speedup 1.0000x reference)
//
#include <hip/hip_runtime.h>
#include <math.h>

#define B_   128
#define R_   1152
#define C_   16
#define O_   16
#define RS_  128
#define RCH_ 9             // R_/RS_
#define NBLK 1024          // 8 bt x 128 rs
#define SLICE_P 8464       // f4 per k-slice: 8192 + 272 pad (non-pow2 channel rotation)

// ws float offsets
#define WS_SP   0          // RS_*SLICE_P*4 = 4333568
#define WS_V    4333568    // 32768
#define WS_BLOG 4366336    // 18432
#define WS_CTRL 4384768    // 768 floats: cs0 at +256 (stride 16), cs1 at +512 (stride 16)
#define WS_WT   4385536    // 2359296 (Wt4[r*512 + d*64 + co4])

__device__ __forceinline__ float squashf(float s) {
    return s * fabsf(s) / (1.0f + s * s);
}

// ---------- G: sp[rs][b][co] = sum_{r in chunk,i} x[b,r,i]*cw[r,c]*W[r,co,i]
// grid 1024 x 256 (4 blocks/CU -> 4 waves/SIMD). XCD-swizzled: bid%8 -> 16-chunk
// rs-group per XCD (Wt slice 1.2 MB L2-resident).
// MODE 0 (iter 0): cw = 1/R exactly; reads RAW W (per-lane-contiguous 128 B
//   fragments, L1-amortized) and writes transposed Wt as a side effect (bt==0
//   blocks only); block 0 zeroes the colsum control area.
// MODE 1: reads coalesced Wt; cw = exp(blog)*1/colsum (colsum from prior a_k).
template <int MODE>
__global__ __launch_bounds__(256, 4) void gemm_s_k(const float* __restrict__ x,
                                                   const float* __restrict__ W,
                                                   float* __restrict__ wt,
                                                   const float* __restrict__ blog,
                                                   const float* __restrict__ colsum,
                                                   float* __restrict__ sp,
                                                   float* __restrict__ ctrl) {
    const int bid = blockIdx.x;
    const int xcd = bid & 7;
    const int g   = bid >> 3;                 // 0..127
    const int rs  = xcd * 16 + (g & 15);      // XCD owns rs in [16*xcd, 16*xcd+16)
    const int bt  = g >> 4;                   // 0..7
    const int t   = threadIdx.x;
    const int co4 = t & 63;
    const int b4  = t >> 6;
    const int c   = co4 >> 2;
    const int r0  = rs * RCH_;

    __shared__ float4 xl4[16 * RCH_ * 2];     // 288 f4 = 4.6 KB
    __shared__ float  cwl[RCH_ * 16];         // 144
    __shared__ float  colinv_sh[16];

    const float4* __restrict__ X4  = (const float4*)x;
    const float4* __restrict__ W4  = (const float4*)W;
    float4* __restrict__ Wt4 = (float4*)wt;

    if (MODE == 0 && bid == 0) {              // zero colsum area before any a_k
        for (int u = t; u < 768; u += 256) ctrl[u] = 0.0f;
    }

    // stage x tile: 16 b x 9 r x 2 f4
    #pragma unroll
    for (int k = 0; k < 2; ++k) {
        const int u = t + k * 256;
        if (u < 16 * RCH_ * 2) {
            const int bl = u / (RCH_ * 2), rem = u % (RCH_ * 2);
            xl4[u] = X4[((bt * 16 + bl) * R_ + r0) * 2 + rem];
        }
    }

    // cheap prepass: cwl[rl][cc] = exp(blog)*1/colsum
    if (MODE != 0) {
        if (t < 16) colinv_sh[t] = 1.0f / colsum[t * 16];
        __syncthreads();
        if (t < RCH_ * 16) {
            const int rl = t >> 4, cc = t & 15;
            cwl[t] = __expf(blog[(r0 + rl) * 16 + cc]) * colinv_sh[cc];
        }
    }
    __syncthreads();

    float acc[4][4];
    #pragma unroll
    for (int j = 0; j < 4; ++j)
        #pragma unroll
        for (int q = 0; q < 4; ++q) acc[j][q] = 0.f;

    #pragma unroll 3
    for (int rr = 0; rr < RCH_; ++rr) {
        float4 w[8];
        if (MODE == 0) {
            // raw layout: thread's 8 fragments are 128 B contiguous
            const float4* wp = W4 + ((size_t)(r0 + rr) << 9) + co4 * 8;
            #pragma unroll
            for (int q = 0; q < 8; ++q) w[q] = wp[q];
            if (bt == 0) {                     // build Wt for later kernels
                float4* wo = Wt4 + ((size_t)(r0 + rr) << 9) + co4;
                #pragma unroll
                for (int q = 0; q < 8; ++q) wo[q * 64] = w[q];
            }
        } else {
            // transposed layout: lane-coalesced 1 KB per load
            const float4* wp = Wt4 + ((size_t)(r0 + rr) << 9) + co4;
            #pragma unroll
            for (int q = 0; q < 8; ++q) w[q] = wp[q * 64];
        }
        const float cwv = (MODE == 0) ? (1.0f / (float)R_) : cwl[rr * 16 + c];
        #pragma unroll
        for (int j = 0; j < 4; ++j) {
            const float4 xa = xl4[(b4 * 4 + j) * (RCH_ * 2) + rr * 2];
            const float4 xb = xl4[(b4 * 4 + j) * (RCH_ * 2) + rr * 2 + 1];
            const float d0 = w[0].x*xa.x + w[0].y*xa.y + w[0].z*xa.z + w[0].w*xa.w
                           + w[1].x*xb.x + w[1].y*xb.y + w[1].z*xb.z + w[1].w*xb.w;
            const float d1 = w[2].x*xa.x + w[2].y*xa.y + w[2].z*xa.z + w[2].w*xa.w
                           + w[3].x*xb.x + w[3].y*xb.y + w[3].z*xb.z + w[3].w*xb.w;
            const float d2 = w[4].x*xa.x + w[4].y*xa.y + w[4].z*xa.z + w[4].w*xa.w
                           + w[5].x*xb.x + w[5].y*xb.y + w[5].z*xb.z + w[5].w*xb.w;
            const float d3 = w[6].x*xa.x + w[6].y*xa.y + w[6].z*xa.z + w[6].w*xa.w
                           + w[7].x*xb.x + w[7].y*xb.y + w[7].z*xb.z + w[7].w*xb.w;
            acc[j][0] = fmaf(cwv, d0, acc[j][0]);
            acc[j][1] = fmaf(cwv, d1, acc[j][1]);
            acc[j][2] = fmaf(cwv, d2, acc[j][2]);
            acc[j][3] = fmaf(cwv, d3, acc[j][3]);
        }
    }

    // write partials (coalesced; slice pitch non-pow2)
    float4* sp4 = (float4*)sp;
    #pragma unroll
    for (int j = 0; j < 4; ++j) {
        const int b = bt * 16 + b4 * 4 + j;
        float4 o4; o4.x = acc[j][0]; o4.y = acc[j][1]; o4.z = acc[j][2]; o4.w = acc[j][3];
        sp4[(size_t)rs * SLICE_P + b * 64 + co4] = o4;
    }
}

// ---------- R: v[b,co] = squash(sum_k sp[k][b][co]) -----------------------
// grid 256 x 256 (65K threads): block owns 32 out-f4, 8-way k-split (16 slices
// per thread) + LDS tree. Fully parallel, coalesced 512 B segments.
__global__ __launch_bounds__(256, 4) void reduce_squash_k(const float* __restrict__ sp,
                                                          float* __restrict__ dst) {
    const int t  = threadIdx.x;
    const int o4 = blockIdx.x * 32 + (t & 31);
    const int kq = t >> 5;                    // 0..7
    const float4* __restrict__ sp4 = (const float4*)sp;
    float4 a; a.x = 0.f; a.y = 0.f; a.z = 0.f; a.w = 0.f;
    #pragma unroll
    for (int k = 0; k < 16; ++k) {
        const float4 u = sp4[(size_t)(kq * 16 + k) * SLICE_P + o4];
        a.x += u.x; a.y += u.y; a.z += u.z; a.w += u.w;
    }
    __shared__ float4 red[256];
    red[t] = a;
    __syncthreads();
    if (t < 32) {
        float ax = 0.f, ay = 0.f, az = 0.f, aw = 0.f;
        #pragma unroll
        for (int j = 0; j < 8; ++j) {
            const float4 p = red[t + 32 * j];
            ax += p.x; ay += p.y; az += p.z; aw += p.w;
        }
        float4 o;
        o.x = squashf(ax); o.y = squashf(ay); o.z = squashf(az); o.w = squashf(aw);
        ((float4*)dst)[o4] = o;
    }
}

// ---------- A: blog[r,c] (+)= (1/B) sum_{b,o} u_hat[b,r,co]*v[b,co]
// grid 576 x 256 (2 r per block; waves: rr=w&1, half=w>>1). Accumulates
// colsum[c*16] += exp(new_blog) (padded counters -> parallel atomics).
template <bool FIRST>
__global__ __launch_bounds__(256, 4) void a_k(const float* __restrict__ x,
                                              const float* __restrict__ wt,
                                              const float* __restrict__ v,
                                              float* __restrict__ blog,
                                              float* __restrict__ colsum) {
    const int r0 = blockIdx.x * 2;
    const int t  = threadIdx.x;
    const int w  = t >> 6, lane = t & 63;
    const int rr = w & 1, half = w >> 1;
    const int co4 = lane, c = lane >> 2;

    __shared__ float4 xl[128 * 4];        // 128 b x 2 r x 2 f4 = 8 KB
    __shared__ float  red[64];
    const float4* __restrict__ X4  = (const float4*)x;
    const float4* __restrict__ V4  = (const float4*)v;
    const float4* __restrict__ Wt4 = (const float4*)wt;

    #pragma unroll
    for (int kk = 0; kk < 2; ++kk) {
        const int u = t + kk * 256;       // 0..511
        const int b = u >> 2, rem = u & 3;
        xl[u] = X4[(b * R_ + r0) * 2 + rem];
    }
    __syncthreads();

    float y[8][4];
    #pragma unroll
    for (int i = 0; i < 8; ++i)
        #pragma unroll
        for (int q = 0; q < 4; ++q) y[i][q] = 0.f;

    const int b0 = half * 64;
    #pragma unroll 4
    for (int bb = 0; bb < 64; ++bb) {
        const int b = b0 + bb;
        const float4 xa = xl[b * 4 + rr * 2];
        const float4 xb = xl[b * 4 + rr * 2 + 1];
        const float4 vv = V4[b * 64 + co4];
        const float xs[8] = {xa.x, xa.y, xa.z, xa.w, xb.x, xb.y, xb.z, xb.w};
        #pragma unroll
        for (int i = 0; i < 8; ++i) {
            y[i][0] = fmaf(xs[i], vv.x, y[i][0]);
            y[i][1] = fmaf(xs[i], vv.y, y[i][1]);
            y[i][2] = fmaf(xs[i], vv.z, y[i][2]);
            y[i][3] = fmaf(xs[i], vv.w, y[i][3]);
        }
    }

    const float4* wp = Wt4 + ((size_t)(r0 + rr) << 9) + co4;
    float part = 0.f;
    #pragma unroll
    for (int q = 0; q < 4; ++q) {
        const float4 w0 = wp[(2 * q) * 64];
        const float4 w1 = wp[(2 * q + 1) * 64];
        part += w0.x*y[0][q] + w0.y*y[1][q] + w0.z*y[2][q] + w0.w*y[3][q]
              + w1.x*y[4][q] + w1.y*y[5][q] + w1.z*y[6][q] + w1.w*y[7][q];
    }
    part += __shfl_xor(part, 1);
    part += __shfl_xor(part, 2);
    if ((lane & 3) == 0) red[w * 16 + c] = part;
    __syncthreads();
    if (t < 32) {
        const int rr2 = t >> 4, cc = t & 15;
        const float val = (red[rr2 * 16 + cc] + red[(2 + rr2) * 16 + cc])
                          * (1.0f / (float)B_);
        const int idx = (r0 + rr2) * 16 + cc;
        const float nv = FIRST ? val : (blog[idx] + val);
        blog[idx] = nv;
        atomicAdd(&colsum[cc * 16], __expf(nv));   // softmax denom for next gemm
    }
}

extern "C" void kernel_launch(void* const* d_in, const int* in_sizes, int n_in,
                              void* d_out, int out_size, void* d_ws, size_t ws_size,
                              hipStream_t stream) {
    const float* x = (const float*)d_in[0];   // [128,1152,8]
    const float* W = (const float*)d_in[1];   // [1,1152,16,16,8]
    float* out = (float*)d_out;               // [128,16,16]
    float* ws  = (float*)d_ws;                // ~25.7 MB used

    float* sp   = ws + WS_SP;
    float* v    = ws + WS_V;
    float* blog = ws + WS_BLOG;
    float* ctrl = ws + WS_CTRL;
    float* wt   = ws + WS_WT;

    float* cs0 = ctrl + 256;                  // 16 counters, stride 16 floats
    float* cs1 = ctrl + 512;

    // iter 0 (softmax(0) == 1/R): reads raw W, emits Wt + zeroed colsums
    gemm_s_k<0><<<NBLK, 256, 0, stream>>>(x, W, wt, nullptr, nullptr, sp, ctrl);
    reduce_squash_k<<<256, 256, 0, stream>>>(sp, v);
    a_k<true ><<<576, 256, 0, stream>>>(x, wt, v, blog, cs0);

    // iter 1
    gemm_s_k<1><<<NBLK, 256, 0, stream>>>(x, nullptr, wt, blog, cs0, sp, ctrl);
    reduce_squash_k<<<256, 256, 0, stream>>>(sp, v);
    a_k<false><<<576, 256, 0, stream>>>(x, wt, v, blog, cs1);

    // iter 2 — reduce writes squash(s) directly to out
    gemm_s_k<1><<<NBLK, 256, 0, stream>>>(x, nullptr, wt, blog, cs1, sp, ctrl);
    reduce_squash_k<<<256, 256, 0, stream>>>(sp, out);
}

// Round 5
// 225.567 us; speedup vs baseline: 1.2497x; 1.2497x over previous
//
#include <hip/hip_runtime.h>
#include <math.h>

#define B_   128
#define R_   1152
#define C_   16
#define O_   16
#define RS_  64
#define RCH_ 18            // R_/RS_

// ws float offsets (R0 layout + ctrl block)
#define WS_SP   0          // RS_*32768 = 2097152
#define WS_V    2097152    // 32768
#define WS_BLOG 2129920    // 18432
#define WS_CTRL 2148352    // 768 floats: cs0 at +256 (stride 16), cs1 at +512 (stride 16)
#define WS_WT   2149120    // 2359296 (Wt4[r*512 + d*64 + co4])

__device__ __forceinline__ float squashf(float s) {
    return s * fabsf(s) / (1.0f + s * s);
}

// ---------- T: Wt4[r*512 + d*64 + co4] = W4[r*512 + co4*8 + d]  (pitch-65 LDS swizzle)
//             + zero the colsum control area once per run
__global__ __launch_bounds__(512) void wtrans_k(const float* __restrict__ W,
                                                float* __restrict__ wt,
                                                float* __restrict__ ctrl) {
    const int r = blockIdx.x;
    const int t = threadIdx.x;
    __shared__ float4 sh[520];
    const float4* __restrict__ W4 = (const float4*)W;
    float4* __restrict__ Wt4 = (float4*)wt;

    if (r == 0) {
        for (int u = t; u < 768; u += 512) ctrl[u] = 0.0f;
    }

    sh[(t & 7) * 65 + (t >> 3)] = W4[r * 512 + t];     // t = co4*8 + d
    __syncthreads();
    Wt4[r * 512 + t] = sh[(t >> 6) * 65 + (t & 63)];   // t = d*64 + co4
}

// ---------- G: sp[rs][b][co] = sum_{r in chunk,i} x[b,r,i]*cw[r,c]*W[r,co,i]
// grid 512 x 256 (R0 structure). 1-D bid with XCD swizzle: bid%8 -> 8-chunk
// rs-group per XCD (Wt slice 1.15 MB + x slice 0.6 MB L2-resident per XCD).
// FIRST: cw = 1/R exactly. Else: cw = exp(blog)*1/colsum, colsum from prior a_k
// (replaces R0's full per-block softmax prepass).
template <bool FIRST>
__global__ __launch_bounds__(256) void gemm_s_k(const float* __restrict__ x,
                                                const float* __restrict__ wt,
                                                const float* __restrict__ blog,
                                                const float* __restrict__ colsum,
                                                float* __restrict__ sp) {
    const int bid = blockIdx.x;
    const int rs  = (bid & 7) * 8 + ((bid >> 3) & 7);   // XCD (bid%8) owns rs-group
    const int bt  = bid >> 6;                           // 0..7
    const int t   = threadIdx.x;
    const int co4 = t & 63;
    const int b4  = t >> 6;
    const int c   = co4 >> 2;
    const int r0  = rs * RCH_;

    __shared__ float4 xl4[576];         // 16 b x 18 r x 2 f4 = 9 KB
    __shared__ float  cwl[RCH_ * 16];   // 288
    __shared__ float  colinv_sh[16];

    const float4* __restrict__ X4  = (const float4*)x;
    const float4* __restrict__ Wt4 = (const float4*)wt;

    // stage x tile (R0-identical)
    #pragma unroll
    for (int k = 0; k < 3; ++k) {
        const int u = t + k * 256;
        if (u < 576) {
            const int bl = u / 36, rem = u % 36;
            xl4[u] = X4[((bt * 16 + bl) * R_ + r0) * 2 + rem];
        }
    }

    // cheap prepass: cwl[rl][cc] = exp(blog)*1/colsum (colsum built by previous a_k)
    if (!FIRST) {
        if (t < 16) colinv_sh[t] = 1.0f / colsum[t * 16];
        __syncthreads();
        for (int u2 = t; u2 < RCH_ * 16; u2 += 256) {
            const int rl = u2 >> 4, cc = u2 & 15;
            cwl[u2] = __expf(blog[(r0 + rl) * 16 + cc]) * colinv_sh[cc];
        }
    }
    __syncthreads();

    float acc[4][4];
    #pragma unroll
    for (int j = 0; j < 4; ++j)
        #pragma unroll
        for (int q = 0; q < 4; ++q) acc[j][q] = 0.f;

    // R0-identical hot loop (plain launch_bounds, unroll 3, named w0..w7)
    #pragma unroll 3
    for (int rr = 0; rr < RCH_; ++rr) {
        const float cwv = FIRST ? (1.0f / (float)R_) : cwl[rr * 16 + c];
        const float4* wp = Wt4 + ((size_t)(r0 + rr) << 9) + co4;   // lane-stride 16B
        const float4 w0 = wp[  0], w1 = wp[ 64], w2 = wp[128], w3 = wp[192];
        const float4 w4 = wp[256], w5 = wp[320], w6 = wp[384], w7 = wp[448];
        #pragma unroll
        for (int j = 0; j < 4; ++j) {
            const float4 xa = xl4[(b4 * 4 + j) * 36 + rr * 2];
            const float4 xb = xl4[(b4 * 4 + j) * 36 + rr * 2 + 1];
            const float d0 = w0.x*xa.x + w0.y*xa.y + w0.z*xa.z + w0.w*xa.w
                           + w1.x*xb.x + w1.y*xb.y + w1.z*xb.z + w1.w*xb.w;
            const float d1 = w2.x*xa.x + w2.y*xa.y + w2.z*xa.z + w2.w*xa.w
                           + w3.x*xb.x + w3.y*xb.y + w3.z*xb.z + w3.w*xb.w;
            const float d2 = w4.x*xa.x + w4.y*xa.y + w4.z*xa.z + w4.w*xa.w
                           + w5.x*xb.x + w5.y*xb.y + w5.z*xb.z + w5.w*xb.w;
            const float d3 = w6.x*xa.x + w6.y*xa.y + w6.z*xa.z + w6.w*xa.w
                           + w7.x*xb.x + w7.y*xb.y + w7.z*xb.z + w7.w*xb.w;
            acc[j][0] = fmaf(cwv, d0, acc[j][0]);
            acc[j][1] = fmaf(cwv, d1, acc[j][1]);
            acc[j][2] = fmaf(cwv, d2, acc[j][2]);
            acc[j][3] = fmaf(cwv, d3, acc[j][3]);
        }
    }

    float4* sp4 = (float4*)sp;
    #pragma unroll
    for (int j = 0; j < 4; ++j) {
        const int b = bt * 16 + b4 * 4 + j;
        float4 o4; o4.x = acc[j][0]; o4.y = acc[j][1]; o4.z = acc[j][2]; o4.w = acc[j][3];
        sp4[(rs * B_ + b) * 64 + co4] = o4;
    }
}

// ---------- R: v[b,co] = squash(sum_k sp[k][b][co]); grid 256 x 512, k-split x4
// (R0-identical)
__global__ __launch_bounds__(512) void reduce_squash_k(const float* __restrict__ sp,
                                                       float* __restrict__ outv) {
    const int t   = threadIdx.x;
    const int li  = t & 127;
    const int kq  = t >> 7;               // 0..3 (16 slices each)
    const int idx = blockIdx.x * 128 + li;
    const float* p = sp + (size_t)kq * 16 * 32768 + idx;
    float a0 = 0.f, a1 = 0.f, a2 = 0.f, a3 = 0.f;
    #pragma unroll
    for (int k = 0; k < 16; k += 4) {
        a0 += p[(k + 0) * 32768];
        a1 += p[(k + 1) * 32768];
        a2 += p[(k + 2) * 32768];
        a3 += p[(k + 3) * 32768];
    }
    __shared__ float red[512];
    red[t] = (a0 + a1) + (a2 + a3);
    __syncthreads();
    if (t < 128) {
        const float s = (red[t] + red[t + 128]) + (red[t + 256] + red[t + 384]);
        outv[idx] = squashf(s);
    }
}

// ---------- A: blog[r,c] (+)= (1/B) sum_{b,o} u_hat[b,r,co]*v[b,co] ----------
// grid 288 x 512 (R0-identical) + padded colsum atomics for next gemm's softmax.
template <bool FIRST>
__global__ __launch_bounds__(512) void a_k(const float* __restrict__ x,
                                           const float* __restrict__ wt,
                                           const float* __restrict__ v,
                                           float* __restrict__ blog,
                                           float* __restrict__ colsum) {
    const int r0 = blockIdx.x * 4;
    const int t  = threadIdx.x;
    const int w  = t >> 6, lane = t & 63;
    const int rr = w & 3, half = w >> 2;
    const int co4 = lane, c = lane >> 2;

    __shared__ float4 xl[128 * 8];        // 16 KB
    __shared__ float  red[128];
    const float4* __restrict__ X4  = (const float4*)x;
    const float4* __restrict__ V4  = (const float4*)v;
    const float4* __restrict__ Wt4 = (const float4*)wt;

    #pragma unroll
    for (int kk = 0; kk < 2; ++kk) {
        const int u = t + kk * 512;       // 0..1023
        const int b = u >> 3, rem = u & 7;
        xl[u] = X4[(b * R_ + r0) * 2 + rem];
    }
    __syncthreads();

    float y[8][4];
    #pragma unroll
    for (int i = 0; i < 8; ++i)
        #pragma unroll
        for (int q = 0; q < 4; ++q) y[i][q] = 0.f;

    const int b0 = half * 64;
    #pragma unroll 4
    for (int bb = 0; bb < 64; ++bb) {
        const int b = b0 + bb;
        const float4 xa = xl[b * 8 + rr * 2];
        const float4 xb = xl[b * 8 + rr * 2 + 1];
        const float4 vv = V4[b * 64 + co4];
        const float xs[8] = {xa.x, xa.y, xa.z, xa.w, xb.x, xb.y, xb.z, xb.w};
        #pragma unroll
        for (int i = 0; i < 8; ++i) {
            y[i][0] = fmaf(xs[i], vv.x, y[i][0]);
            y[i][1] = fmaf(xs[i], vv.y, y[i][1]);
            y[i][2] = fmaf(xs[i], vv.z, y[i][2]);
            y[i][3] = fmaf(xs[i], vv.w, y[i][3]);
        }
    }

    const float4* wp = Wt4 + ((size_t)(r0 + rr) << 9) + co4;
    float part = 0.f;
    #pragma unroll
    for (int q = 0; q < 4; ++q) {
        const float4 w0 = wp[(2 * q) * 64];
        const float4 w1 = wp[(2 * q + 1) * 64];
        part += w0.x*y[0][q] + w0.y*y[1][q] + w0.z*y[2][q] + w0.w*y[3][q]
              + w1.x*y[4][q] + w1.y*y[5][q] + w1.z*y[6][q] + w1.w*y[7][q];
    }
    part += __shfl_xor(part, 1);
    part += __shfl_xor(part, 2);
    if ((lane & 3) == 0) red[w * 16 + c] = part;
    __syncthreads();
    if (t < 64) {
        const int rr2 = t >> 4, cc = t & 15;
        const float val = (red[rr2 * 16 + cc] + red[(rr2 + 4) * 16 + cc]) * (1.0f / (float)B_);
        const int idx = (r0 + rr2) * 16 + cc;
        const float nv = FIRST ? val : (blog[idx] + val);
        blog[idx] = nv;
        atomicAdd(&colsum[cc * 16], __expf(nv));   // softmax denom for next gemm
    }
}

extern "C" void kernel_launch(void* const* d_in, const int* in_sizes, int n_in,
                              void* d_out, int out_size, void* d_ws, size_t ws_size,
                              hipStream_t stream) {
    const float* x = (const float*)d_in[0];   // [128,1152,8]
    const float* W = (const float*)d_in[1];   // [1,1152,16,16,8]
    float* out = (float*)d_out;               // [128,16,16]
    float* ws  = (float*)d_ws;                // ~18 MB used

    float* sp   = ws + WS_SP;
    float* v    = ws + WS_V;
    float* blog = ws + WS_BLOG;
    float* ctrl = ws + WS_CTRL;
    float* wt   = ws + WS_WT;

    float* cs0 = ctrl + 256;                  // 16 counters, stride 16 floats
    float* cs1 = ctrl + 512;

    // build Wt once (coalesced transpose) + zero colsums
    wtrans_k<<<R_, 512, 0, stream>>>(W, wt, ctrl);

    // iter 0 (softmax(0) == 1/R exactly)
    gemm_s_k<true ><<<512, 256, 0, stream>>>(x, wt, nullptr, nullptr, sp);
    reduce_squash_k<<<256, 512, 0, stream>>>(sp, v);
    a_k<true ><<<288, 512, 0, stream>>>(x, wt, v, blog, cs0);

    // iter 1
    gemm_s_k<false><<<512, 256, 0, stream>>>(x, wt, blog, cs0, sp);
    reduce_squash_k<<<256, 512, 0, stream>>>(sp, v);
    a_k<false><<<288, 512, 0, stream>>>(x, wt, v, blog, cs1);

    // iter 2
    gemm_s_k<false><<<512, 256, 0, stream>>>(x, wt, blog, cs1, sp);
    reduce_squash_k<<<256, 512, 0, stream>>>(sp, out);
}

// Round 6
// 167.475 us; speedup vs baseline: 1.6832x; 1.3469x over previous
//
#include <hip/hip_runtime.h>
#include <math.h>

#define B_   128
#define R_   1152
#define C_   16
#define O_   16
#define RS_  64
#define RCH_ 18            // R_/RS_
#define NBINS 72           // 1152/16 colsum bins

// ws float offsets
#define WS_SP   0          // RS_*32768 = 2097152
#define WS_V    2097152    // 32768
#define WS_BLOG 2129920    // 18432
#define WS_CTRL 2148352    // 2560 floats: cs0 bins @+0 (72*16), cs1 bins @+1280
#define WS_WT   2150912    // 2359296 (Wt4[r*512 + d*64 + co4])

__device__ __forceinline__ float squashf(float s) {
    return s * fabsf(s) / (1.0f + s * s);
}

// ---------- T: Wt4[r*512 + d*64 + co4] = W4[r*512 + co4*8 + d]  (pitch-65 LDS swizzle)
//             + zero the colsum bin area once per run
__global__ __launch_bounds__(512) void wtrans_k(const float* __restrict__ W,
                                                float* __restrict__ wt,
                                                float* __restrict__ ctrl) {
    const int r = blockIdx.x;
    const int t = threadIdx.x;
    __shared__ float4 sh[520];
    const float4* __restrict__ W4 = (const float4*)W;
    float4* __restrict__ Wt4 = (float4*)wt;

    if (r == 0) {
        for (int u = t; u < 2560; u += 512) ctrl[u] = 0.0f;
    }

    sh[(t & 7) * 65 + (t >> 3)] = W4[r * 512 + t];     // t = co4*8 + d
    __syncthreads();
    Wt4[r * 512 + t] = sh[(t >> 6) * 65 + (t & 63)];   // t = d*64 + co4
}

// ---------- G: sp[rs][b][co] = sum_{r in chunk,i} x[b,r,i]*cw[r,c]*W[r,co,i]
// grid dim3(8 bt, RS_ rs) x 256 — R0's exact proven structure and hot loop.
// FIRST: cw = 1/R exactly. Else cw = exp(blog)*1/colsum, where colsum is
// reassembled from 72 x 16 bins written by the previous a_k (replaces R0's
// full 73KB blog re-read + 4.6K exp per block).
template <bool FIRST>
__global__ __launch_bounds__(256) void gemm_s_k(const float* __restrict__ x,
                                                const float* __restrict__ wt,
                                                const float* __restrict__ blog,
                                                const float* __restrict__ colbins,
                                                float* __restrict__ sp) {
    const int bt  = blockIdx.x;
    const int rs  = blockIdx.y;
    const int t   = threadIdx.x;
    const int co4 = t & 63;
    const int b4  = t >> 6;
    const int c   = co4 >> 2;
    const int r0  = rs * RCH_;

    __shared__ float4 xl4[576];         // 16 b x 18 r x 2 f4 = 9 KB
    __shared__ float  cwl[RCH_ * 16];   // 288
    __shared__ float  colinv_sh[16];
    __shared__ float  psum[256];

    const float4* __restrict__ X4  = (const float4*)x;
    const float4* __restrict__ Wt4 = (const float4*)wt;

    // stage x tile (R0-identical)
    #pragma unroll
    for (int k = 0; k < 3; ++k) {
        const int u = t + k * 256;
        if (u < 576) {
            const int bl = u / 36, rem = u % 36;
            xl4[u] = X4[((bt * 16 + bl) * R_ + r0) * 2 + rem];
        }
    }

    // prepass: colinv from bins (parallel 16 j-lanes x 16 cc), then cwl rows
    if (!FIRST) {
        const int cc = t & 15, jb = t >> 4;
        float s = 0.f;
        for (int j = jb; j < NBINS; j += 16) s += colbins[j * 16 + cc];
        psum[t] = s;
        __syncthreads();
        if (t < 16) {
            float tot = 0.f;
            #pragma unroll
            for (int k2 = 0; k2 < 16; ++k2) tot += psum[k2 * 16 + t];
            colinv_sh[t] = 1.0f / tot;
        }
        __syncthreads();
        for (int u2 = t; u2 < RCH_ * 16; u2 += 256) {
            const int rl = u2 >> 4, c2 = u2 & 15;
            cwl[u2] = __expf(blog[(r0 + rl) * 16 + c2]) * colinv_sh[c2];
        }
    }
    __syncthreads();

    float acc[4][4];
    #pragma unroll
    for (int j = 0; j < 4; ++j)
        #pragma unroll
        for (int q = 0; q < 4; ++q) acc[j][q] = 0.f;

    // R0-identical hot loop
    #pragma unroll 3
    for (int rr = 0; rr < RCH_; ++rr) {
        const float cwv = FIRST ? (1.0f / (float)R_) : cwl[rr * 16 + c];
        const float4* wp = Wt4 + ((size_t)(r0 + rr) << 9) + co4;   // lane-stride 16B
        const float4 w0 = wp[  0], w1 = wp[ 64], w2 = wp[128], w3 = wp[192];
        const float4 w4 = wp[256], w5 = wp[320], w6 = wp[384], w7 = wp[448];
        #pragma unroll
        for (int j = 0; j < 4; ++j) {
            const float4 xa = xl4[(b4 * 4 + j) * 36 + rr * 2];
            const float4 xb = xl4[(b4 * 4 + j) * 36 + rr * 2 + 1];
            const float d0 = w0.x*xa.x + w0.y*xa.y + w0.z*xa.z + w0.w*xa.w
                           + w1.x*xb.x + w1.y*xb.y + w1.z*xb.z + w1.w*xb.w;
            const float d1 = w2.x*xa.x + w2.y*xa.y + w2.z*xa.z + w2.w*xa.w
                           + w3.x*xb.x + w3.y*xb.y + w3.z*xb.z + w3.w*xb.w;
            const float d2 = w4.x*xa.x + w4.y*xa.y + w4.z*xa.z + w4.w*xa.w
                           + w5.x*xb.x + w5.y*xb.y + w5.z*xb.z + w5.w*xb.w;
            const float d3 = w6.x*xa.x + w6.y*xa.y + w6.z*xa.z + w6.w*xa.w
                           + w7.x*xb.x + w7.y*xb.y + w7.z*xb.z + w7.w*xb.w;
            acc[j][0] = fmaf(cwv, d0, acc[j][0]);
            acc[j][1] = fmaf(cwv, d1, acc[j][1]);
            acc[j][2] = fmaf(cwv, d2, acc[j][2]);
            acc[j][3] = fmaf(cwv, d3, acc[j][3]);
        }
    }

    float4* sp4 = (float4*)sp;
    #pragma unroll
    for (int j = 0; j < 4; ++j) {
        const int b = bt * 16 + b4 * 4 + j;
        float4 o4; o4.x = acc[j][0]; o4.y = acc[j][1]; o4.z = acc[j][2]; o4.w = acc[j][3];
        sp4[(rs * B_ + b) * 64 + co4] = o4;
    }
}

// ---------- R: v[b,co] = squash(sum_k sp[k][b][co]); grid 256 x 512 (R0-identical)
__global__ __launch_bounds__(512) void reduce_squash_k(const float* __restrict__ sp,
                                                       float* __restrict__ outv) {
    const int t   = threadIdx.x;
    const int li  = t & 127;
    const int kq  = t >> 7;               // 0..3 (16 slices each)
    const int idx = blockIdx.x * 128 + li;
    const float* p = sp + (size_t)kq * 16 * 32768 + idx;
    float a0 = 0.f, a1 = 0.f, a2 = 0.f, a3 = 0.f;
    #pragma unroll
    for (int k = 0; k < 16; k += 4) {
        a0 += p[(k + 0) * 32768];
        a1 += p[(k + 1) * 32768];
        a2 += p[(k + 2) * 32768];
        a3 += p[(k + 3) * 32768];
    }
    __shared__ float red[512];
    red[t] = (a0 + a1) + (a2 + a3);
    __syncthreads();
    if (t < 128) {
        const float s = (red[t] + red[t + 128]) + (red[t + 256] + red[t + 384]);
        outv[idx] = squashf(s);
    }
}

// ---------- A: blog[r,c] (+)= (1/B) sum_{b,o} u_hat[b,r,co]*v[b,co] ----------
// REBUILT: grid 1152 x 256 (1 r/block; 4 waves = batch quarters of 32 b).
// launch_bounds(256,2) -> VGPR cap 256 so y[8][4] stays in registers
// (R0..R5 version allocated 36 VGPR -> accumulators in scratch -> 49 us).
// Tail: exp(new_blog) into 72x16 colsum bins (16-deep atomic chains).
template <bool FIRST>
__global__ __launch_bounds__(256, 2) void a_k(const float* __restrict__ x,
                                              const float* __restrict__ wt,
                                              const float* __restrict__ v,
                                              float* __restrict__ blog,
                                              float* __restrict__ colbins) {
    const int r = blockIdx.x;
    const int t = threadIdx.x;
    const int w = t >> 6, lane = t & 63;
    const int co4 = lane, c = lane >> 2;

    __shared__ float4 xl[256];            // 128 b x 2 f4 = 4 KB
    __shared__ float  red[64];
    const float4* __restrict__ X4  = (const float4*)x;
    const float4* __restrict__ V4  = (const float4*)v;
    const float4* __restrict__ Wt4 = (const float4*)wt;

    xl[t] = X4[((t >> 1) * R_ + r) * 2 + (t & 1)];
    __syncthreads();

    float y[8][4];
    #pragma unroll
    for (int i = 0; i < 8; ++i)
        #pragma unroll
        for (int q = 0; q < 4; ++q) y[i][q] = 0.f;

    const int b0 = w * 32;
    #pragma unroll 4
    for (int bb = 0; bb < 32; ++bb) {
        const int b = b0 + bb;
        const float4 xa = xl[b * 2];
        const float4 xb = xl[b * 2 + 1];
        const float4 vv = V4[b * 64 + co4];
        y[0][0] = fmaf(xa.x, vv.x, y[0][0]); y[0][1] = fmaf(xa.x, vv.y, y[0][1]);
        y[0][2] = fmaf(xa.x, vv.z, y[0][2]); y[0][3] = fmaf(xa.x, vv.w, y[0][3]);
        y[1][0] = fmaf(xa.y, vv.x, y[1][0]); y[1][1] = fmaf(xa.y, vv.y, y[1][1]);
        y[1][2] = fmaf(xa.y, vv.z, y[1][2]); y[1][3] = fmaf(xa.y, vv.w, y[1][3]);
        y[2][0] = fmaf(xa.z, vv.x, y[2][0]); y[2][1] = fmaf(xa.z, vv.y, y[2][1]);
        y[2][2] = fmaf(xa.z, vv.z, y[2][2]); y[2][3] = fmaf(xa.z, vv.w, y[2][3]);
        y[3][0] = fmaf(xa.w, vv.x, y[3][0]); y[3][1] = fmaf(xa.w, vv.y, y[3][1]);
        y[3][2] = fmaf(xa.w, vv.z, y[3][2]); y[3][3] = fmaf(xa.w, vv.w, y[3][3]);
        y[4][0] = fmaf(xb.x, vv.x, y[4][0]); y[4][1] = fmaf(xb.x, vv.y, y[4][1]);
        y[4][2] = fmaf(xb.x, vv.z, y[4][2]); y[4][3] = fmaf(xb.x, vv.w, y[4][3]);
        y[5][0] = fmaf(xb.y, vv.x, y[5][0]); y[5][1] = fmaf(xb.y, vv.y, y[5][1]);
        y[5][2] = fmaf(xb.y, vv.z, y[5][2]); y[5][3] = fmaf(xb.y, vv.w, y[5][3]);
        y[6][0] = fmaf(xb.z, vv.x, y[6][0]); y[6][1] = fmaf(xb.z, vv.y, y[6][1]);
        y[6][2] = fmaf(xb.z, vv.z, y[6][2]); y[6][3] = fmaf(xb.z, vv.w, y[6][3]);
        y[7][0] = fmaf(xb.w, vv.x, y[7][0]); y[7][1] = fmaf(xb.w, vv.y, y[7][1]);
        y[7][2] = fmaf(xb.w, vv.z, y[7][2]); y[7][3] = fmaf(xb.w, vv.w, y[7][3]);
    }

    const float4* wp = Wt4 + ((size_t)r << 9) + co4;
    float part = 0.f;
    #pragma unroll
    for (int q = 0; q < 4; ++q) {
        const float4 w0 = wp[(2 * q) * 64];
        const float4 w1 = wp[(2 * q + 1) * 64];
        part += w0.x*y[0][q] + w0.y*y[1][q] + w0.z*y[2][q] + w0.w*y[3][q]
              + w1.x*y[4][q] + w1.y*y[5][q] + w1.z*y[6][q] + w1.w*y[7][q];
    }
    part += __shfl_xor(part, 1);
    part += __shfl_xor(part, 2);
    if ((lane & 3) == 0) red[w * 16 + c] = part;
    __syncthreads();
    if (t < 16) {
        const float val = ((red[t] + red[16 + t]) + (red[32 + t] + red[48 + t]))
                          * (1.0f / (float)B_);
        const int idx = r * 16 + t;
        const float nv = FIRST ? val : (blog[idx] + val);
        blog[idx] = nv;
        atomicAdd(&colbins[(r >> 4) * 16 + t], __expf(nv));  // 16-deep chains
    }
}

extern "C" void kernel_launch(void* const* d_in, const int* in_sizes, int n_in,
                              void* d_out, int out_size, void* d_ws, size_t ws_size,
                              hipStream_t stream) {
    const float* x = (const float*)d_in[0];   // [128,1152,8]
    const float* W = (const float*)d_in[1];   // [1,1152,16,16,8]
    float* out = (float*)d_out;               // [128,16,16]
    float* ws  = (float*)d_ws;                // ~18 MB used

    float* sp   = ws + WS_SP;
    float* v    = ws + WS_V;
    float* blog = ws + WS_BLOG;
    float* ctrl = ws + WS_CTRL;
    float* wt   = ws + WS_WT;

    float* cs0 = ctrl;                        // 72x16 bins
    float* cs1 = ctrl + 1280;                 // 72x16 bins (64B-aligned)

    // build Wt once (coalesced transpose) + zero colsum bins
    wtrans_k<<<R_, 512, 0, stream>>>(W, wt, ctrl);

    // iter 0 (softmax(0) == 1/R exactly)
    gemm_s_k<true ><<<dim3(8, RS_), 256, 0, stream>>>(x, wt, nullptr, nullptr, sp);
    reduce_squash_k<<<256, 512, 0, stream>>>(sp, v);
    a_k<true ><<<R_, 256, 0, stream>>>(x, wt, v, blog, cs0);

    // iter 1
    gemm_s_k<false><<<dim3(8, RS_), 256, 0, stream>>>(x, wt, blog, cs0, sp);
    reduce_squash_k<<<256, 512, 0, stream>>>(sp, v);
    a_k<false><<<R_, 256, 0, stream>>>(x, wt, v, blog, cs1);

    // iter 2
    gemm_s_k<false><<<dim3(8, RS_), 256, 0, stream>>>(x, wt, blog, cs1, sp);
    reduce_squash_k<<<256, 512, 0, stream>>>(sp, out);
}